// Round 6
// baseline (205.681 us; speedup 1.0000x reference)
//
#include <hip/hip_runtime.h>
#include <math.h>

#define N_NODES 50000
#define N_REL   1000
#define D       128
#define NNZ     800000

#define G       64              // edge chunks
#define CHUNK   (NNZ / G)       // 12500 edges per chunk
#define P       2               // row passes
#define HALF    (N_NODES / P)   // 25000 rows per pass
#define SCAN_N  (N_NODES * G)   // 3,200,000 table entries
#define SCAN_B  (SCAN_N / 1024) // 3125 scan blocks (1024 elems each)

// ---------------- kernel 1: per-relation exp(leaky_relu(score)) ----------------
__global__ void scores_kernel(const float* __restrict__ dual,
                              const float* __restrict__ conv_w,
                              const float* __restrict__ conv_b,
                              float* __restrict__ exp_scores,
                              float* __restrict__ denom) {
    int r = blockIdx.x;
    int t = threadIdx.x;                    // 0..63
    const float* row = dual + (long)r * D;
    float s = row[t] * conv_w[t] + row[t + 64] * conv_w[t + 64];
    #pragma unroll
    for (int off = 32; off > 0; off >>= 1)
        s += __shfl_down(s, off);
    if (t == 0) {
        float v = s + conv_b[0];
        v = (v >= 0.f) ? v : 0.01f * v;     // leaky_relu
        exp_scores[r] = expf(v);            // scores ~N(0,1): safe w/o max-sub
        if (r == 0) *denom = 0.f;
    }
}

// ------ phase A: per-(chunk,half) LDS histogram -> count table; fused denom ------
// grid (G, P) x 1024 threads. Packed u16 counts (<=12500, no overflow).
__global__ void phaseA_kernel(const int* __restrict__ rows,
                              const int* __restrict__ rel,
                              const float* __restrict__ exp_scores,
                              unsigned* __restrict__ table,
                              float* __restrict__ denom) {
    __shared__ unsigned h[HALF / 2];        // 12500 dwords = 50 KB
    __shared__ float wpart[16];
    int b = blockIdx.x;                     // chunk
    int p = blockIdx.y;                     // row half
    int t = threadIdx.x;
    for (int i = t; i < HALF / 2; i += 1024) h[i] = 0;
    __syncthreads();
    int cbase = b * CHUNK;
    int rlo = p * HALF;
    float dsum = 0.f;
    for (int k = 0; k < (CHUNK + 1023) / 1024; ++k) {
        int j = t + k * 1024;
        if (j < CHUNK) {
            int e = cbase + j;
            int r = rows[e];
            if (p == 0) dsum += exp_scores[rel[e]];   // denom: count each edge once
            unsigned rl = (unsigned)(r - rlo);
            if (rl < (unsigned)HALF)
                atomicAdd(&h[rl >> 1], 1u << ((rl & 1) * 16));
        }
    }
    if (p == 0) {                            // block-reduce dsum, one atomic/block
        #pragma unroll
        for (int off = 32; off > 0; off >>= 1)
            dsum += __shfl_down(dsum, off);
        if ((t & 63) == 0) wpart[t >> 6] = dsum;
        __syncthreads();
        if (t == 0) {
            float v = 0.f;
            #pragma unroll
            for (int k = 0; k < 16; ++k) v += wpart[k];
            atomicAdd(denom, v);
        }
    }
    __syncthreads();
    for (int i = t; i < HALF; i += 1024) {
        unsigned cnt = (h[i >> 1] >> ((i & 1) * 16)) & 0xFFFFu;
        table[(unsigned)(rlo + i) * G + b] = cnt;
    }
}

// -------- scanA: in-place block-local exclusive scan over table (uint4) --------
__global__ void scanA_kernel(unsigned* __restrict__ a,
                             unsigned* __restrict__ bsums) {
    __shared__ unsigned wsum[4];
    int t = threadIdx.x;                    // 0..255
    int lane = t & 63;
    int w = t >> 6;
    int i = blockIdx.x * 1024 + t * 4;
    uint4 x = *(const uint4*)(a + i);
    unsigned s0 = x.x, s01 = x.x + x.y, s012 = s01 + x.z;
    unsigned ts = s012 + x.w;
    unsigned v = ts;
    #pragma unroll
    for (int off = 1; off < 64; off <<= 1) {
        unsigned y = __shfl_up(v, off);
        if (lane >= off) v += y;
    }
    if (lane == 63) wsum[w] = v;
    __syncthreads();
    if (t == 0) {
        unsigned acc = 0;
        #pragma unroll
        for (int k = 0; k < 4; ++k) { unsigned tmp = wsum[k]; wsum[k] = acc; acc += tmp; }
        bsums[blockIdx.x] = acc;
    }
    __syncthreads();
    unsigned ex = wsum[w] + (v - ts);
    uint4 o; o.x = ex; o.y = ex + s0; o.z = ex + s01; o.w = ex + s012;
    *(uint4*)(a + i) = o;
}

// -------- scanB: scan the 3125 block sums (1 block x 1024, 4 tiles) --------
__global__ void scanB_kernel(unsigned* __restrict__ bsums,
                             int* __restrict__ offsets) {
    __shared__ unsigned wsum[16];
    __shared__ unsigned carry;
    int t = threadIdx.x;
    int lane = t & 63;
    int w = t >> 6;
    if (t == 0) carry = 0;
    __syncthreads();
    for (int tile = 0; tile < 4; ++tile) {
        int i = tile * 1024 + t;
        unsigned x = (i < SCAN_B) ? bsums[i] : 0;
        unsigned v = x;
        #pragma unroll
        for (int off = 1; off < 64; off <<= 1) {
            unsigned y = __shfl_up(v, off);
            if (lane >= off) v += y;
        }
        if (lane == 63) wsum[w] = v;
        __syncthreads();
        if (t == 0) {
            unsigned acc = 0;
            #pragma unroll
            for (int k = 0; k < 16; ++k) { unsigned tmp = wsum[k]; wsum[k] = acc; acc += tmp; }
            wsum[15] = wsum[15];  // no-op; total added to carry below
            carry += 0;           // placeholder (updated after writes)
            // stash total in shared via wpart-free path: reuse carry after sync
        }
        __syncthreads();
        unsigned ex = carry + wsum[w] + (v - x);
        if (i < SCAN_B) bsums[i] = ex;
        // compute tile total = last wave's inclusive end: recover via reduction
        __syncthreads();
        if (t == 1023) wsum[0] = wsum[15] + v;   // wsum[15]=excl of wave15; v=incl in wave
        __syncthreads();
        if (t == 0) carry += wsum[0];
        __syncthreads();
    }
    if (t == 0) offsets[N_NODES] = NNZ;
}

// -------- scanC: add block prefix; emit per-row CSR offsets --------
__global__ void scanC_kernel(unsigned* __restrict__ a,
                             const unsigned* __restrict__ bsums,
                             int* __restrict__ offsets) {
    int t = threadIdx.x;
    int i = blockIdx.x * 1024 + t * 4;
    unsigned add = bsums[blockIdx.x];
    uint4 x = *(const uint4*)(a + i);
    x.x += add; x.y += add; x.z += add; x.w += add;
    *(uint4*)(a + i) = x;
    if ((i & (G - 1)) == 0) offsets[i / G] = (int)x.x;   // i % 64 == 0 -> row start
}

// ------ phase C: re-count in LDS as cursors; place edges; weight on the fly ------
__global__ void phaseC_kernel(const int* __restrict__ rows,
                              const int* __restrict__ cols,
                              const int* __restrict__ rel,
                              const float* __restrict__ exp_scores,
                              const float* __restrict__ denom,
                              const unsigned* __restrict__ table,
                              int2* __restrict__ bpack) {
    __shared__ unsigned h[HALF / 2];        // packed u16 cursors
    int b = blockIdx.x;
    int p = blockIdx.y;
    int t = threadIdx.x;
    for (int i = t; i < HALF / 2; i += 1024) h[i] = 0;
    __syncthreads();
    float inv = 1.0f / *denom;
    int cbase = b * CHUNK;
    int rlo = p * HALF;
    for (int k = 0; k < (CHUNK + 1023) / 1024; ++k) {
        int j = t + k * 1024;
        if (j < CHUNK) {
            int e = cbase + j;
            int r = rows[e];
            unsigned rl = (unsigned)(r - rlo);
            if (rl < (unsigned)HALF) {
                int c = cols[e];
                float wv = exp_scores[rel[e]] * inv;
                unsigned shift = (rl & 1) * 16;
                unsigned old = atomicAdd(&h[rl >> 1], 1u << shift);
                unsigned lrank = (old >> shift) & 0xFFFFu;
                unsigned pos = table[(unsigned)r * G + b] + lrank;
                int2 pk; pk.x = c; pk.y = __float_as_int(wv);
                bpack[pos] = pk;
            }
        }
    }
}

// ------ gather: float4/lane, 32 lanes/row, 2 rows per load, MLP=8 --------
__global__ void gather_kernel(const int* __restrict__ offsets,
                              const int2* __restrict__ bpack,
                              const float* __restrict__ inlayer,
                              float* __restrict__ out) {
    int node = blockIdx.x * (blockDim.x >> 6) + (threadIdx.x >> 6);
    int lane = threadIdx.x & 63;
    if (node >= N_NODES) return;
    int s = offsets[node];
    int e = offsets[node + 1];
    int half = lane >> 5;
    int l32  = lane & 31;
    float4 acc; acc.x = 0.f; acc.y = 0.f; acc.z = 0.f; acc.w = 0.f;
    for (int base = s; base < e; base += 64) {
        int rem = e - base; if (rem > 64) rem = 64;
        int px = 0, py = 0;
        if (lane < rem) {
            int2 p = bpack[base + lane];
            px = p.x; py = p.y;
        }
        for (int j = 0; j < rem; j += 8) {
            #pragma unroll
            for (int k = 0; k < 8; k += 2) {
                int idx = j + k + half;
                int   c = __shfl(px, idx);
                float w = __int_as_float(__shfl(py, idx));
                float4 v = ((const float4*)(inlayer + (long)c * D))[l32];
                acc.x += w * v.x; acc.y += w * v.y;
                acc.z += w * v.z; acc.w += w * v.w;
            }
        }
    }
    float4 tot;
    tot.x = acc.x + __shfl(acc.x, lane ^ 32);
    tot.y = acc.y + __shfl(acc.y, lane ^ 32);
    tot.z = acc.z + __shfl(acc.z, lane ^ 32);
    tot.w = acc.w + __shfl(acc.w, lane ^ 32);
    if (lane < 32)
        ((float4*)(out + (long)node * D))[l32] = tot;
}

extern "C" void kernel_launch(void* const* d_in, const int* in_sizes, int n_in,
                              void* d_out, int out_size, void* d_ws, size_t ws_size,
                              hipStream_t stream) {
    const float* inlayer  = (const float*)d_in[0];
    const float* dual     = (const float*)d_in[1];
    const float* conv_w   = (const float*)d_in[2];
    const float* conv_b   = (const float*)d_in[3];
    const int*   edge_idx = (const int*)d_in[4];   // [2, NNZ]: rows then cols
    const int*   edge_rel = (const int*)d_in[5];
    float* out = (float*)d_out;
    const int* rows = edge_idx;
    const int* cols = edge_idx + NNZ;

    // workspace layout (all 16B aligned)
    char* ws = (char*)d_ws;
    float*    exp_scores = (float*)   (ws);                 // 1000 f
    float*    denom      = (float*)   (ws + 4096);          // 1 f
    int*      offsets    = (int*)     (ws + 8192);          // 50001 i
    unsigned* table      = (unsigned*)(ws + 212992);        // 3.2M u32 (12.8 MB)
    unsigned* bsums      = (unsigned*)(ws + 13012992);      // 3125 u32
    int2*     bpack      = (int2*)    (ws + 13029376);      // 800000 int2 (6.4 MB)

    scores_kernel<<<N_REL, 64, 0, stream>>>(dual, conv_w, conv_b,
                                            exp_scores, denom);

    phaseA_kernel<<<dim3(G, P), 1024, 0, stream>>>(rows, edge_rel, exp_scores,
                                                   table, denom);

    scanA_kernel<<<SCAN_B, 256, 0, stream>>>(table, bsums);
    scanB_kernel<<<1, 1024, 0, stream>>>(bsums, offsets);
    scanC_kernel<<<SCAN_B, 256, 0, stream>>>(table, bsums, offsets);

    phaseC_kernel<<<dim3(G, P), 1024, 0, stream>>>(rows, cols, edge_rel,
                                                   exp_scores, denom, table, bpack);

    int grid = (N_NODES + 3) / 4;   // 4 waves/block, one node per wave
    gather_kernel<<<grid, 256, 0, stream>>>(offsets, bpack, inlayer, out);
}

// Round 7
// 202.631 us; speedup vs baseline: 1.0151x; 1.0151x over previous
//
#include <hip/hip_runtime.h>
#include <math.h>

#define N_NODES 50000
#define N_REL   1000
#define D       128
#define NNZ     800000

#define G       64               // edge chunks
#define CHUNK   (NNZ / G)        // 12500 edges per chunk
#define P       8                // row ranges
#define RNG     (N_NODES / P)    // 6250 rows per range
#define SCAN_N  (N_NODES * G)    // 3,200,000 table entries
#define SCAN_BLKS (SCAN_N / 1024) // 3125 scanA blocks

// ---------------- kernel 1: per-relation exp(leaky_relu(score)) ----------------
__global__ void scores_kernel(const float* __restrict__ dual,
                              const float* __restrict__ conv_w,
                              const float* __restrict__ conv_b,
                              float* __restrict__ exp_scores,
                              float* __restrict__ denom) {
    int r = blockIdx.x;
    int t = threadIdx.x;                    // 0..63
    const float* row = dual + (long)r * D;
    float s = row[t] * conv_w[t] + row[t + 64] * conv_w[t + 64];
    #pragma unroll
    for (int off = 32; off > 0; off >>= 1)
        s += __shfl_down(s, off);
    if (t == 0) {
        float v = s + conv_b[0];
        v = (v >= 0.f) ? v : 0.01f * v;     // leaky_relu
        exp_scores[r] = expf(v);            // scores ~N(0,1): safe w/o max-sub
        if (r == 0) *denom = 0.f;
    }
}

// ------ phase A: per-(chunk,range) LDS u16 histogram -> count table; fused denom ------
// grid (G=64, P=8) x 512 threads. Counts <= 12500, no u16 overflow.
__global__ void phaseA_kernel(const int* __restrict__ rows,
                              const int* __restrict__ rel,
                              const float* __restrict__ exp_scores,
                              unsigned* __restrict__ table,
                              float* __restrict__ denom) {
    __shared__ unsigned h[RNG / 2];         // 3125 dwords = 12.5 KB
    __shared__ float wpart[8];
    int b = blockIdx.x;                     // chunk
    int p = blockIdx.y;                     // row range
    int t = threadIdx.x;                    // 0..511
    for (int i = t; i < RNG / 2; i += 512) h[i] = 0;
    __syncthreads();
    int cbase4 = b * (CHUNK / 4);
    int rlo = p * RNG;
    float dsum = 0.f;
    for (int j = t; j < CHUNK / 4; j += 512) {
        int4 rr = ((const int4*)rows)[cbase4 + j];
        if (p == 0) {                       // denom: each edge counted once
            int4 rl = ((const int4*)rel)[cbase4 + j];
            dsum += exp_scores[rl.x] + exp_scores[rl.y]
                  + exp_scores[rl.z] + exp_scores[rl.w];
        }
        unsigned u;
        u = (unsigned)(rr.x - rlo); if (u < (unsigned)RNG) atomicAdd(&h[u >> 1], 1u << ((u & 1) * 16));
        u = (unsigned)(rr.y - rlo); if (u < (unsigned)RNG) atomicAdd(&h[u >> 1], 1u << ((u & 1) * 16));
        u = (unsigned)(rr.z - rlo); if (u < (unsigned)RNG) atomicAdd(&h[u >> 1], 1u << ((u & 1) * 16));
        u = (unsigned)(rr.w - rlo); if (u < (unsigned)RNG) atomicAdd(&h[u >> 1], 1u << ((u & 1) * 16));
    }
    if (p == 0) {                           // block-reduce dsum, one atomic/block
        #pragma unroll
        for (int off = 32; off > 0; off >>= 1)
            dsum += __shfl_down(dsum, off);
        if ((t & 63) == 0) wpart[t >> 6] = dsum;
        __syncthreads();
        if (t == 0) {
            float v = 0.f;
            #pragma unroll
            for (int k = 0; k < 8; ++k) v += wpart[k];
            atomicAdd(denom, v);
        }
    }
    __syncthreads();
    for (int i = t; i < RNG; i += 512) {
        unsigned cnt = (h[i >> 1] >> ((i & 1) * 16)) & 0xFFFFu;
        table[(unsigned)(rlo + i) * G + b] = cnt;
    }
}

// -------- scanA: block-local exclusive scan over table (uint4, 1024/block) --------
__global__ void scanA_kernel(unsigned* __restrict__ a,
                             unsigned* __restrict__ bsums) {
    __shared__ unsigned wsum[4];
    int t = threadIdx.x;                    // 0..255
    int lane = t & 63;
    int w = t >> 6;
    int i = blockIdx.x * 1024 + t * 4;
    uint4 x = *(const uint4*)(a + i);
    unsigned s0 = x.x, s01 = x.x + x.y, s012 = s01 + x.z;
    unsigned ts = s012 + x.w;
    unsigned v = ts;
    #pragma unroll
    for (int off = 1; off < 64; off <<= 1) {
        unsigned y = __shfl_up(v, off);
        if (lane >= off) v += y;
    }
    if (lane == 63) wsum[w] = v;
    __syncthreads();
    if (t == 0) {
        unsigned acc = 0;
        #pragma unroll
        for (int k = 0; k < 4; ++k) { unsigned tmp = wsum[k]; wsum[k] = acc; acc += tmp; }
        bsums[blockIdx.x] = acc;
    }
    __syncthreads();
    unsigned ex = wsum[w] + (v - ts);
    uint4 o; o.x = ex; o.y = ex + s0; o.z = ex + s01; o.w = ex + s012;
    *(uint4*)(a + i) = o;
}

// -------- scanB: exclusive scan of 3125 block sums (one block, 1024 thr x 4) --------
__global__ void scanB_kernel(unsigned* __restrict__ bsums,
                             int* __restrict__ offsets) {
    __shared__ unsigned wsum[16];
    int t = threadIdx.x;                    // 0..1023
    int lane = t & 63;
    int w = t >> 6;
    int i = t * 4;
    unsigned x0 = (i     < SCAN_BLKS) ? bsums[i]     : 0;
    unsigned x1 = (i + 1 < SCAN_BLKS) ? bsums[i + 1] : 0;
    unsigned x2 = (i + 2 < SCAN_BLKS) ? bsums[i + 2] : 0;
    unsigned x3 = (i + 3 < SCAN_BLKS) ? bsums[i + 3] : 0;
    unsigned s0 = x0, s01 = x0 + x1, s012 = s01 + x2;
    unsigned ts = s012 + x3;
    unsigned v = ts;
    #pragma unroll
    for (int off = 1; off < 64; off <<= 1) {
        unsigned y = __shfl_up(v, off);
        if (lane >= off) v += y;
    }
    if (lane == 63) wsum[w] = v;
    __syncthreads();
    if (t == 0) {
        unsigned acc = 0;
        #pragma unroll
        for (int k = 0; k < 16; ++k) { unsigned tmp = wsum[k]; wsum[k] = acc; acc += tmp; }
    }
    __syncthreads();
    unsigned ex = wsum[w] + (v - ts);
    if (i     < SCAN_BLKS) bsums[i]     = ex;
    if (i + 1 < SCAN_BLKS) bsums[i + 1] = ex + s0;
    if (i + 2 < SCAN_BLKS) bsums[i + 2] = ex + s01;
    if (i + 3 < SCAN_BLKS) bsums[i + 3] = ex + s012;
    if (t == 0) offsets[N_NODES] = NNZ;
}

// -------- scanC: add block prefix; emit per-row CSR offsets --------
__global__ void scanC_kernel(unsigned* __restrict__ a,
                             const unsigned* __restrict__ bsums,
                             int* __restrict__ offsets) {
    int t = threadIdx.x;
    int i = blockIdx.x * 1024 + t * 4;
    unsigned add = bsums[blockIdx.x];
    uint4 x = *(const uint4*)(a + i);
    x.x += add; x.y += add; x.z += add; x.w += add;
    *(uint4*)(a + i) = x;
    if ((i & (G - 1)) == 0) offsets[i / G] = (int)x.x;   // logical (r, b=0) -> row start
}

// ------ phase C: LDS cursors; place edges; weight on the fly ------
__global__ void phaseC_kernel(const int* __restrict__ rows,
                              const int* __restrict__ cols,
                              const int* __restrict__ rel,
                              const float* __restrict__ exp_scores,
                              const float* __restrict__ denom,
                              const unsigned* __restrict__ table,
                              int2* __restrict__ bpack) {
    __shared__ unsigned h[RNG / 2];         // packed u16 cursors
    int b = blockIdx.x;
    int p = blockIdx.y;
    int t = threadIdx.x;
    for (int i = t; i < RNG / 2; i += 512) h[i] = 0;
    __syncthreads();
    float inv = 1.0f / *denom;
    int cbase4 = b * (CHUNK / 4);
    int rlo = p * RNG;
    for (int j = t; j < CHUNK / 4; j += 512) {
        int4 rr = ((const int4*)rows)[cbase4 + j];
        int4 cc = ((const int4*)cols)[cbase4 + j];
        int4 rl = ((const int4*)rel)[cbase4 + j];
        #pragma unroll
        for (int k = 0; k < 4; ++k) {
            int r = (k == 0) ? rr.x : (k == 1) ? rr.y : (k == 2) ? rr.z : rr.w;
            int c = (k == 0) ? cc.x : (k == 1) ? cc.y : (k == 2) ? cc.z : cc.w;
            int q = (k == 0) ? rl.x : (k == 1) ? rl.y : (k == 2) ? rl.z : rl.w;
            unsigned u = (unsigned)(r - rlo);
            if (u < (unsigned)RNG) {
                unsigned shift = (u & 1) * 16;
                unsigned old = atomicAdd(&h[u >> 1], 1u << shift);
                unsigned lrank = (old >> shift) & 0xFFFFu;
                unsigned pos = table[(unsigned)r * G + b] + lrank;
                int2 pk; pk.x = c; pk.y = __float_as_int(exp_scores[q] * inv);
                bpack[pos] = pk;
            }
        }
    }
}

// ------ gather: float4/lane, 32 lanes/row, 2 rows per load, MLP=8 --------
__global__ void gather_kernel(const int* __restrict__ offsets,
                              const int2* __restrict__ bpack,
                              const float* __restrict__ inlayer,
                              float* __restrict__ out) {
    int node = blockIdx.x * (blockDim.x >> 6) + (threadIdx.x >> 6);
    int lane = threadIdx.x & 63;
    if (node >= N_NODES) return;
    int s = offsets[node];
    int e = offsets[node + 1];
    int half = lane >> 5;
    int l32  = lane & 31;
    float4 acc; acc.x = 0.f; acc.y = 0.f; acc.z = 0.f; acc.w = 0.f;
    for (int base = s; base < e; base += 64) {
        int rem = e - base; if (rem > 64) rem = 64;
        int px = 0, py = 0;
        if (lane < rem) {
            int2 p = bpack[base + lane];
            px = p.x; py = p.y;
        }
        for (int j = 0; j < rem; j += 8) {
            #pragma unroll
            for (int k = 0; k < 8; k += 2) {
                int idx = j + k + half;
                int   c = __shfl(px, idx);
                float w = __int_as_float(__shfl(py, idx));
                float4 v = ((const float4*)(inlayer + (long)c * D))[l32];
                acc.x += w * v.x; acc.y += w * v.y;
                acc.z += w * v.z; acc.w += w * v.w;
            }
        }
    }
    float4 tot;
    tot.x = acc.x + __shfl(acc.x, lane ^ 32);
    tot.y = acc.y + __shfl(acc.y, lane ^ 32);
    tot.z = acc.z + __shfl(acc.z, lane ^ 32);
    tot.w = acc.w + __shfl(acc.w, lane ^ 32);
    if (lane < 32)
        ((float4*)(out + (long)node * D))[l32] = tot;
}

extern "C" void kernel_launch(void* const* d_in, const int* in_sizes, int n_in,
                              void* d_out, int out_size, void* d_ws, size_t ws_size,
                              hipStream_t stream) {
    const float* inlayer  = (const float*)d_in[0];
    const float* dual     = (const float*)d_in[1];
    const float* conv_w   = (const float*)d_in[2];
    const float* conv_b   = (const float*)d_in[3];
    const int*   edge_idx = (const int*)d_in[4];   // [2, NNZ]: rows then cols
    const int*   edge_rel = (const int*)d_in[5];
    float* out = (float*)d_out;
    const int* rows = edge_idx;
    const int* cols = edge_idx + NNZ;

    // workspace layout (16B aligned)
    char* ws = (char*)d_ws;
    float*    exp_scores = (float*)   (ws);                 // 1000 f
    float*    denom      = (float*)   (ws + 4096);          // 1 f
    int*      offsets    = (int*)     (ws + 8192);          // 50001 i
    unsigned* table      = (unsigned*)(ws + 212992);        // 3.2M u32 (12.8 MB)
    unsigned* bsums      = (unsigned*)(ws + 13012992);      // 3125 u32
    int2*     bpack      = (int2*)    (ws + 13029376);      // 800000 int2 (6.4 MB)

    scores_kernel<<<N_REL, 64, 0, stream>>>(dual, conv_w, conv_b,
                                            exp_scores, denom);

    phaseA_kernel<<<dim3(G, P), 512, 0, stream>>>(rows, edge_rel, exp_scores,
                                                  table, denom);

    scanA_kernel<<<SCAN_BLKS, 256, 0, stream>>>(table, bsums);
    scanB_kernel<<<1, 1024, 0, stream>>>(bsums, offsets);
    scanC_kernel<<<SCAN_BLKS, 256, 0, stream>>>(table, bsums, offsets);

    phaseC_kernel<<<dim3(G, P), 512, 0, stream>>>(rows, cols, edge_rel,
                                                  exp_scores, denom, table, bpack);

    int grid = (N_NODES + 3) / 4;   // 4 waves/block, one node per wave
    gather_kernel<<<grid, 256, 0, stream>>>(offsets, bpack, inlayer, out);
}